// Round 13
// baseline (131.981 us; speedup 1.0000x reference)
//
#include <hip/hip_runtime.h>
#include <stdint.h>

typedef unsigned short u16;
typedef unsigned long long u64;
typedef _Float16 f16;
typedef __attribute__((ext_vector_type(8))) _Float16 f16x8;   // 8 fp16 MFMA frag
typedef __attribute__((ext_vector_type(4))) float f32x4;      // 16x16 MFMA accumulator
typedef __attribute__((ext_vector_type(16))) float f32x16;    // 32x32 MFMA accumulator
typedef __attribute__((ext_vector_type(4))) unsigned short u16x4;
typedef __attribute__((ext_vector_type(8))) unsigned short u16x8;

#define NHEADS 16
#define DMODEL 1024
#define DHEAD 64
#define SEQ 2048
#define NBATCH 2
#define MROWS (NBATCH * SEQ)   /* 4096 */
#define NQKV 3072
#define SCQ 0.18033688011112042f   /* (1/8) * log2(e), folded into Q */

__device__ __forceinline__ u16 f2h(float x) {
  union { f16 h; u16 u; } v;
  v.h = (f16)x;                  // v_cvt_f16_f32, RNE
  return v.u;
}

__device__ __forceinline__ unsigned pk2u(float x, float y) {
  typedef __fp16 fp16x2 __attribute__((ext_vector_type(2)));
  fp16x2 h = __builtin_amdgcn_cvt_pkrtz(x, y);   // v_cvt_pkrtz_f16_f32
  union { fp16x2 h; unsigned u; } v; v.h = h;
  return v.u;
}

__device__ __forceinline__ f16x8 mkfrag(unsigned w0, unsigned w1, unsigned w2, unsigned w3) {
  union { unsigned u[4]; f16x8 f; } t;
  t.u[0] = w0; t.u[1] = w1; t.u[2] = w2; t.u[3] = w3;
  return t.f;
}

// V B-fragment with the custom k-slot map kappa(F,j,hi) = 16F + (j&3) + 8*(j>>2) + 4*hi.
__device__ __forceinline__ f16x8 vfrag(const char* row, int sz, int F, int hib8) {
  union { u64 u[2]; f16x8 f; } t;
  t.u[0] = *(const u64*)(row + (((2 * F) ^ sz) << 4) + hib8);
  t.u[1] = *(const u64*)(row + (((2 * F + 1) ^ sz) << 4) + hib8);
  return t.f;
}

__device__ __forceinline__ void gload_lds16(const void* g, void* l) {
  __builtin_amdgcn_global_load_lds(
      (const __attribute__((address_space(1))) void*)g,
      (__attribute__((address_space(3))) void*)l, 16, 0, 0);
}

// ---------------- merged prep kernel ----------------
// blocks [0,2048): X fp32 -> fp16            (8 elems/thread)
// blocks [2048,2816): W_QKV transpose->fp16  (LDS transpose, coalesced)
// blocks [2816,3072): W_O transpose->fp16
__global__ __launch_bounds__(256) void prep_kernel(
    const float* __restrict__ X,
    const float* __restrict__ WQ, const float* __restrict__ WK,
    const float* __restrict__ WV, const float* __restrict__ WO,
    u16* __restrict__ Xh, u16* __restrict__ Wqkv, u16* __restrict__ Wo) {
  __shared__ u16 lt[64][72];
  int blk = blockIdx.x;
  if (blk < 2048) {
    int i = blk * 256 + threadIdx.x;
    const f32x4* xv = (const f32x4*)(X + (size_t)i * 8);
    f32x4 a = xv[0], b = xv[1];
    u16x8 o;
    o[0] = f2h(a[0]); o[1] = f2h(a[1]); o[2] = f2h(a[2]); o[3] = f2h(a[3]);
    o[4] = f2h(b[0]); o[5] = f2h(b[1]); o[6] = f2h(b[2]); o[7] = f2h(b[3]);
    *(u16x8*)(Xh + (size_t)i * 8) = o;
  } else if (blk < 2816) {
    // W[h][m][d] -> Wqkv[n][m], n = qkv*1024 + h*64 + d
    int bb = blk - 2048;
    int mt = bb & 15, hh = (bb >> 4) & 15, qkv = bb >> 8;
    const float* W = (qkv == 0) ? WQ : (qkv == 1) ? WK : WV;
    int m_in = threadIdx.x >> 2, dq = threadIdx.x & 3;
    const f32x4* sp4 = (const f32x4*)(W + (size_t)hh * (DMODEL * DHEAD) +
                                      (size_t)(mt * 64 + m_in) * DHEAD + dq * 16);
#pragma unroll
    for (int v4 = 0; v4 < 4; ++v4) {
      f32x4 a = sp4[v4];
#pragma unroll
      for (int j = 0; j < 4; ++j) lt[dq * 16 + v4 * 4 + j][m_in] = f2h(a[j]);
    }
    __syncthreads();
    int d_in = threadIdx.x >> 2, mq = threadIdx.x & 3;
    size_t orow = ((size_t)(qkv * 1024 + hh * 64 + d_in)) * DMODEL + mt * 64 + mq * 16;
    u16x8 o0, o1;
#pragma unroll
    for (int j = 0; j < 8; ++j) {
      o0[j] = lt[d_in][mq * 16 + j];
      o1[j] = lt[d_in][mq * 16 + 8 + j];
    }
    *(u16x8*)(Wqkv + orow) = o0;
    *(u16x8*)(Wqkv + orow + 8) = o1;
  } else {
    // WO[e][m] -> Wo[m][e]
    int bb = blk - 2816;
    int mt = bb & 15, et = bb >> 4;
    int e_in = threadIdx.x >> 2, mq = threadIdx.x & 3;
    const f32x4* sp4 = (const f32x4*)(WO + (size_t)(et * 64 + e_in) * DMODEL + mt * 64 + mq * 16);
#pragma unroll
    for (int v4 = 0; v4 < 4; ++v4) {
      f32x4 a = sp4[v4];
#pragma unroll
      for (int j = 0; j < 4; ++j) lt[mq * 16 + v4 * 4 + j][e_in] = f2h(a[j]);
    }
    __syncthreads();
    int m_in = threadIdx.x >> 2, eq = threadIdx.x & 3;
    size_t orow = (size_t)(mt * 64 + m_in) * DMODEL + et * 64 + eq * 16;
    u16x8 o0, o1;
#pragma unroll
    for (int j = 0; j < 8; ++j) {
      o0[j] = lt[m_in][eq * 16 + j];
      o1[j] = lt[m_in][eq * 16 + 8 + j];
    }
    *(u16x8*)(Wo + orow) = o0;
    *(u16x8*)(Wo + orow + 8) = o1;
  }
}

// ---------------- QKV projection GEMM (fp16, N=3072, fused epilogue) ----------------
__global__ __launch_bounds__(256, 2) void gemm_qkv(
    const u16* __restrict__ A, const u16* __restrict__ Bt,
    const float* __restrict__ bq, const float* __restrict__ bk, const float* __restrict__ bv,
    u16* __restrict__ Qo, u16* __restrict__ Ko, u16* __restrict__ Vto) {
  __shared__ u16 lds[2][8192];
  const int tid = threadIdx.x;
  const int wid = tid >> 6, lane = tid & 63, lr = lane & 15, lg = lane >> 4;
  const int wr = wid >> 1, wc = wid & 1;
  const int brow = blockIdx.y * 128, bcol = blockIdx.x * 128;

  f32x4 acc[4][4];
#pragma unroll
  for (int i = 0; i < 4; ++i)
#pragma unroll
    for (int j = 0; j < 4; ++j) acc[i][j] = (f32x4){0.f, 0.f, 0.f, 0.f};

#define STAGE(buf, kt)                                                               \
  {                                                                                  \
    _Pragma("unroll") for (int i = 0; i < 2; ++i) {                                  \
      int idx = tid + i * 256;                                                       \
      gload_lds16(A + (size_t)(brow + (idx >> 2)) * 1024 + (kt) * 32 + (idx & 3) * 8,\
                  (char*)&lds[buf][0] + (wid * 64 + i * 256) * 16);                  \
    }                                                                                \
    _Pragma("unroll") for (int i = 0; i < 2; ++i) {                                  \
      int idx = tid + i * 256;                                                       \
      gload_lds16(Bt + (size_t)(bcol + (idx >> 2)) * 1024 + (kt) * 32 + (idx & 3) * 8,\
                  (char*)&lds[buf][4096] + (wid * 64 + i * 256) * 16);               \
    }                                                                                \
  }

  STAGE(0, 0);
  __syncthreads();
  int cur = 0;
  for (int kt = 0; kt < 32; ++kt) {
    if (kt + 1 < 32) STAGE(cur ^ 1, kt + 1);
    const u16* Ab = &lds[cur][0];
    const u16* Bb = &lds[cur][4096];
    f16x8 a[4], b[4];
#pragma unroll
    for (int ar = 0; ar < 4; ++ar)
      a[ar] = *(const f16x8*)(Ab + (wr * 64 + ar * 16 + lr) * 32 + lg * 8);
#pragma unroll
    for (int bc = 0; bc < 4; ++bc)
      b[bc] = *(const f16x8*)(Bb + (wc * 64 + bc * 16 + lr) * 32 + lg * 8);
#pragma unroll
    for (int ar = 0; ar < 4; ++ar)
#pragma unroll
      for (int bc = 0; bc < 4; ++bc)
        acc[ar][bc] = __builtin_amdgcn_mfma_f32_16x16x32_f16(a[ar], b[bc], acc[ar][bc], 0, 0, 0);
    __syncthreads();
    cur ^= 1;
  }

#pragma unroll
  for (int ar = 0; ar < 4; ++ar) {
    int row0 = brow + wr * 64 + ar * 16 + lg * 4;
    int bb = row0 >> 11, s0 = row0 & 2047;
#pragma unroll
    for (int bc = 0; bc < 4; ++bc) {
      int n = bcol + wc * 64 + bc * 16 + lr;
      int qkv = n >> 10, hd = n & 1023, h = hd >> 6, d = hd & 63;
      float bias = ((qkv == 0) ? bq : (qkv == 1) ? bk : bv)[hd];
      if (qkv < 2) {
        u16* dst = qkv ? Ko : Qo;
        float sc = qkv ? 1.f : SCQ;
        size_t base = ((size_t)(bb * NHEADS + h) * SEQ + s0) * DHEAD + d;
#pragma unroll
        for (int r = 0; r < 4; ++r)
          dst[base + (size_t)r * DHEAD] = f2h((acc[ar][bc][r] + bias) * sc);
      } else {
        u16x4 o;
        o[0] = f2h(acc[ar][bc][0] + bias);
        o[1] = f2h(acc[ar][bc][1] + bias);
        o[2] = f2h(acc[ar][bc][2] + bias);
        o[3] = f2h(acc[ar][bc][3] + bias);
        *(u16x4*)(Vto + ((size_t)(bb * NHEADS + h) * DHEAD + d) * SEQ + s0) = o;
      }
    }
  }
}

// ---------------- out-projection GEMM (fp16 in, fp32 out) ----------------
__global__ __launch_bounds__(256, 2) void gemm_out(
    const u16* __restrict__ A, const u16* __restrict__ Bt,
    const float* __restrict__ bo, float* __restrict__ Co) {
  __shared__ u16 lds[2][8192];
  const int tid = threadIdx.x;
  const int wid = tid >> 6, lane = tid & 63, lr = lane & 15, lg = lane >> 4;
  const int wr = wid >> 1, wc = wid & 1;
  const int brow = blockIdx.y * 128, bcol = blockIdx.x * 128;

  f32x4 acc[4][4];
#pragma unroll
  for (int i = 0; i < 4; ++i)
#pragma unroll
    for (int j = 0; j < 4; ++j) acc[i][j] = (f32x4){0.f, 0.f, 0.f, 0.f};

  STAGE(0, 0);
  __syncthreads();
  int cur = 0;
  for (int kt = 0; kt < 32; ++kt) {
    if (kt + 1 < 32) STAGE(cur ^ 1, kt + 1);
    const u16* Ab = &lds[cur][0];
    const u16* Bb = &lds[cur][4096];
    f16x8 a[4], b[4];
#pragma unroll
    for (int ar = 0; ar < 4; ++ar)
      a[ar] = *(const f16x8*)(Ab + (wr * 64 + ar * 16 + lr) * 32 + lg * 8);
#pragma unroll
    for (int bc = 0; bc < 4; ++bc)
      b[bc] = *(const f16x8*)(Bb + (wc * 64 + bc * 16 + lr) * 32 + lg * 8);
#pragma unroll
    for (int ar = 0; ar < 4; ++ar)
#pragma unroll
      for (int bc = 0; bc < 4; ++bc)
        acc[ar][bc] = __builtin_amdgcn_mfma_f32_16x16x32_f16(a[ar], b[bc], acc[ar][bc], 0, 0, 0);
    __syncthreads();
    cur ^= 1;
  }
#undef STAGE

#pragma unroll
  for (int ar = 0; ar < 4; ++ar) {
    int row0 = brow + wr * 64 + ar * 16 + lg * 4;
#pragma unroll
    for (int bc = 0; bc < 4; ++bc) {
      int n = bcol + wc * 64 + bc * 16 + lr;
      float bias = bo[n];
#pragma unroll
      for (int r = 0; r < 4; ++r)
        Co[(size_t)(row0 + r) * DMODEL + n] = acc[ar][bc][r] + bias;
    }
  }
}

// ---------------- flash attention: 512 equal-wall blocks x 8 waves, 16 waves/CU ----------------
// Block (p,bh), 512 threads = 8 waves: kp = wid>>1 (k-tiles == kp mod 4, private online
// m/l/acc), qsub = wid&1 (q 32-row half). Tiles {tA=31-p, tB=p} processed sequentially;
// per-block wall = ceil((tA+1)/4) + ceil((tB+1)/4) = 9 for EVERY p -> 2 blocks/CU
// co-resident with identical walls = 16 waves/CU steady, zero idle.
// LDS 64KB: K0..K3 @ kp*8K, V0..V3 @ 32K + kp*8K (single-set; staging anti-phased
// across the 2 co-resident blocks). Q re-staged per tile via K0 region (keeps VGPR low).
// End-of-tile: 2-stage flash-decoding merge over kp (pairs {0,1},{2,3}, then {0,2}/{1,3});
// kp0 stores d-lo, kp1 stores d-hi. 32x32 MFMA layouts + k-slot map identical to R8-R12.
__global__ __launch_bounds__(512, 2) void attn_kernel(
    const u16* __restrict__ Q, const u16* __restrict__ K,
    const u16* __restrict__ Vt, u16* __restrict__ MH) {
  __shared__ char sh8[65536];
  const int tid = threadIdx.x, wid = tid >> 6, lane = tid & 63;
  const int l31 = lane & 31, hi = lane >> 5;
  const int kp = wid >> 1;              // 0..3: k-tile residue class
  const int qsub = wid & 1;             // q 32-row half within the 64-row tile
  const int bid = blockIdx.x;
  const int p = bid >> 5, bh = bid & 31;
  const int h = bh & 15, b = bh >> 4;
  const u16* Qb = Q + (size_t)bh * (SEQ * DHEAD);
  const u16* Kb = K + (size_t)bh * (SEQ * DHEAD);
  const u16* Vb = Vt + (size_t)bh * (DHEAD * SEQ);

  const int sw0 = (l31 ^ (l31 >> 3)) & 7, kz0 = sw0 << 4;
  const int r32 = 32 + l31;
  const int sw1 = (r32 ^ (r32 >> 3)) & 7, kz1 = sw1 << 4;
  const int hib = hi * 16, hib8 = hi * 8;

  // staging: each thread covers one 16B slot of an 8KB (64-row x 128B) tile
  const int srow = tid >> 3;
  const int sseg = (tid & 7) ^ ((srow ^ (srow >> 3)) & 7);

#pragma unroll
  for (int seg = 0; seg < 2; ++seg) {
    const int t = seg ? p : (31 - p);

    // ---- stage Q(t) into K0 region, read frags, release ----
    gload_lds16(Qb + (size_t)(t * 64 + srow) * DHEAD + sseg * 8, sh8 + tid * 16);
    __syncthreads();
    f16x8 qf0, qf1, qf2, qf3;
    {
      int row = (qsub << 5) + l31;
      int swz = ((row ^ (row >> 3)) & 7) << 4;
      const char* qb = sh8 + row * 128;
      qf0 = *(const f16x8*)(qb + ((hib + 0)  ^ swz));
      qf1 = *(const f16x8*)(qb + ((hib + 32) ^ swz));
      qf2 = *(const f16x8*)(qb + ((hib + 64) ^ swz));
      qf3 = *(const f16x8*)(qb + ((hib + 96) ^ swz));
    }
    __syncthreads();   // all waves done reading Q before K0 is restaged

    f32x16 acc0, acc1;
#pragma unroll
    for (int z = 0; z < 16; ++z) { acc0[z] = 0.f; acc1[z] = 0.f; }
    float m = -1e30f, l = 0.f;
    const int qg = t * 64 + (qsub << 5) + l31;   // this lane's absolute q row
    const int wall = (t >> 2) + 1;

    for (int si = 0; si < wall; ++si) {
      // ---- stage this super-iteration's K/V tiles (4 each, <= t) ----
#pragma unroll
      for (int j = 0; j < 4; ++j) {
        int e = 4 * si + j;
        if (e <= t) {
          gload_lds16(Kb + (size_t)(e * 64 + srow) * DHEAD + sseg * 8,
                      sh8 + j * 8192 + tid * 16);
          gload_lds16(Vb + (size_t)srow * SEQ + e * 64 + sseg * 8,
                      sh8 + 32768 + j * 8192 + tid * 16);
        }
      }
      __syncthreads();   // drains staging; tiles ready

      const int kt = 4 * si + kp;
      if (kt <= t) {
        const char* kbuf = sh8 + kp * 8192;

        // ---- QK: S^T[k][q], lane col = q ----
        f32x16 s0, s1;
#pragma unroll
        for (int z = 0; z < 16; ++z) { s0[z] = 0.f; s1[z] = 0.f; }
        {
          const char* kb0 = kbuf + l31 * 128;
          const char* kb1 = kbuf + r32 * 128;
          f16x8 kf;
          __builtin_amdgcn_s_setprio(1);
          kf = *(const f16x8*)(kb0 + ((hib + 0)  ^ kz0)); s0 = __builtin_amdgcn_mfma_f32_32x32x16_f16(kf, qf0, s0, 0, 0, 0);
          kf = *(const f16x8*)(kb0 + ((hib + 32) ^ kz0)); s0 = __builtin_amdgcn_mfma_f32_32x32x16_f16(kf, qf1, s0, 0, 0, 0);
          kf = *(const f16x8*)(kb0 + ((hib + 64) ^ kz0)); s0 = __builtin_amdgcn_mfma_f32_32x32x16_f16(kf, qf2, s0, 0, 0, 0);
          kf = *(const f16x8*)(kb0 + ((hib + 96) ^ kz0)); s0 = __builtin_amdgcn_mfma_f32_32x32x16_f16(kf, qf3, s0, 0, 0, 0);
          kf = *(const f16x8*)(kb1 + ((hib + 0)  ^ kz1)); s1 = __builtin_amdgcn_mfma_f32_32x32x16_f16(kf, qf0, s1, 0, 0, 0);
          kf = *(const f16x8*)(kb1 + ((hib + 32) ^ kz1)); s1 = __builtin_amdgcn_mfma_f32_32x32x16_f16(kf, qf1, s1, 0, 0, 0);
          kf = *(const f16x8*)(kb1 + ((hib + 64) ^ kz1)); s1 = __builtin_amdgcn_mfma_f32_32x32x16_f16(kf, qf2, s1, 0, 0, 0);
          kf = *(const f16x8*)(kb1 + ((hib + 96) ^ kz1)); s1 = __builtin_amdgcn_mfma_f32_32x32x16_f16(kf, qf3, s1, 0, 0, 0);
          __builtin_amdgcn_s_setprio(0);
        }

        // ---- causal mask (diagonal k-tile only): k row = (rr&3)+8*(rr>>2)+4*hi ----
        if (kt == t) {
#pragma unroll
          for (int rr = 0; rr < 16; ++rr) {
            int k0 = kt * 64 + (rr & 3) + 8 * (rr >> 2) + 4 * hi;
            if (k0 > qg) s0[rr] = -1e30f;
            if (k0 + 32 > qg) s1[rr] = -1e30f;
          }
        }

        // ---- per-lane online softmax + 1 shfl_xor(32) per reduction ----
        float tm = s0[0];
#pragma unroll
        for (int rr = 1; rr < 16; ++rr) tm = fmaxf(tm, s0[rr]);
#pragma unroll
        for (int rr = 0; rr < 16; ++rr) tm = fmaxf(tm, s1[rr]);
        tm = fmaxf(tm, __shfl_xor(tm, 32));

        if (!__all(tm <= m + 8.f)) {   // defer-max: rare rescale path
          float m2 = fmaxf(m, tm);
          float al = exp2f(m - m2);
          m = m2;
          l *= al;
#pragma unroll
          for (int rr = 0; rr < 16; ++rr) {
            int qp = (rr & 3) + 8 * (rr >> 2) + 4 * hi;
            float af = __shfl(al, qp);
            acc0[rr] *= af;
            acc1[rr] *= af;
          }
        }

        float rs = 0.f;
#pragma unroll
        for (int rr = 0; rr < 16; ++rr) { s0[rr] = exp2f(s0[rr] - m); rs += s0[rr]; }
#pragma unroll
        for (int rr = 0; rr < 16; ++rr) { s1[rr] = exp2f(s1[rr] - m); rs += s1[rr]; }
        rs += __shfl_xor(rs, 32);
        l += rs;

        // ---- pack P to fp16 A-frags (custom k-slot map, no cross-lane) ----
        f16x8 pa0 = mkfrag(pk2u(s0[0],  s0[1]),  pk2u(s0[2],  s0[3]),
                           pk2u(s0[4],  s0[5]),  pk2u(s0[6],  s0[7]));
        f16x8 pa1 = mkfrag(pk2u(s0[8],  s0[9]),  pk2u(s0[10], s0[11]),
                           pk2u(s0[12], s0[13]), pk2u(s0[14], s0[15]));
        f16x8 pa2 = mkfrag(pk2u(s1[0],  s1[1]),  pk2u(s1[2],  s1[3]),
                           pk2u(s1[4],  s1[5]),  pk2u(s1[6],  s1[7]));
        f16x8 pa3 = mkfrag(pk2u(s1[8],  s1[9]),  pk2u(s1[10], s1[11]),
                           pk2u(s1[12], s1[13]), pk2u(s1[14], s1[15]));

        // ---- PV: O[q][d] += P V, d col = dtile*32 + l31; same k-slot map on V ----
        const char* vbuf = sh8 + 32768 + kp * 8192;
        const char* vr0 = vbuf + l31 * 128;
        const char* vr1 = vbuf + r32 * 128;
        __builtin_amdgcn_s_setprio(1);
        acc0 = __builtin_amdgcn_mfma_f32_32x32x16_f16(pa0, vfrag(vr0, sw0, 0, hib8), acc0, 0, 0, 0);
        acc0 = __builtin_amdgcn_mfma_f32_32x32x16_f16(pa1, vfrag(vr0, sw0, 1, hib8), acc0, 0, 0, 0);
        acc0 = __builtin_amdgcn_mfma_f32_32x32x16_f16(pa2, vfrag(vr0, sw0, 2, hib8), acc0, 0, 0, 0);
        acc0 = __builtin_amdgcn_mfma_f32_32x32x16_f16(pa3, vfrag(vr0, sw0, 3, hib8), acc0, 0, 0, 0);
        acc1 = __builtin_amdgcn_mfma_f32_32x32x16_f16(pa0, vfrag(vr1, sw1, 0, hib8), acc1, 0, 0, 0);
        acc1 = __builtin_amdgcn_mfma_f32_32x32x16_f16(pa1, vfrag(vr1, sw1, 1, hib8), acc1, 0, 0, 0);
        acc1 = __builtin_amdgcn_mfma_f32_32x32x16_f16(pa2, vfrag(vr1, sw1, 2, hib8), acc1, 0, 0, 0);
        acc1 = __builtin_amdgcn_mfma_f32_32x32x16_f16(pa3, vfrag(vr1, sw1, 3, hib8), acc1, 0, 0, 0);
        __builtin_amdgcn_s_setprio(0);
      }
      __syncthreads();   // all waves done with this set before restage
    }

    // ---- 2-stage merge over kp + store ----
    {
      float* z = (float*)sh8 + (size_t)(wid * 64 + lane) * 18;
      const bool keep0 = !(kp & 1);   // even kp keeps acc0 (d-lo), odd keeps acc1 (d-hi)

      // stage 1: partner = kp^1 (wid^2) — both export the acc they DON'T keep
      z[0] = m; z[1] = l;
#pragma unroll
      for (int rr = 0; rr < 16; ++rr) z[2 + rr] = keep0 ? acc1[rr] : acc0[rr];
      __syncthreads();
      {
        const float* y = (const float*)sh8 + (size_t)((wid ^ 2) * 64 + lane) * 18;
        float mb = y[0], lb = y[1];
        float mM = fmaxf(m, mb);
        float aw = exp2f(m - mM), bw = exp2f(mb - mM);
        float lM = l * aw + lb * bw;
#pragma unroll
        for (int rr = 0; rr < 16; ++rr) {
          int qp = (rr & 3) + 8 * (rr >> 2) + 4 * hi;
          float aF = __shfl(aw, qp), bF = __shfl(bw, qp);
          if (keep0) acc0[rr] = acc0[rr] * aF + y[2 + rr] * bF;
          else       acc1[rr] = acc1[rr] * aF + y[2 + rr] * bF;
        }
        m = mM; l = lM;
      }
      __syncthreads();   // stage-1 reads done; slots reusable

      // stage 2: partner = kp^2 (wid^4) — both export the acc they keep; kp<2 stores
      z[0] = m; z[1] = l;
#pragma unroll
      for (int rr = 0; rr < 16; ++rr) z[2 + rr] = keep0 ? acc0[rr] : acc1[rr];
      __syncthreads();
      if (kp < 2) {
        const float* y = (const float*)sh8 + (size_t)((wid ^ 4) * 64 + lane) * 18;
        float mb = y[0], lb = y[1];
        float mM = fmaxf(m, mb);
        float aw = exp2f(m - mM), bw = exp2f(mb - mM);
        float lM = l * aw + lb * bw;
        const int d = keep0 ? l31 : (32 + l31);
#pragma unroll
        for (int rr = 0; rr < 16; ++rr) {
          int qp = (rr & 3) + 8 * (rr >> 2) + 4 * hi;
          float aF = __shfl(aw, qp), bF = __shfl(bw, qp), lF = __shfl(lM, qp);
          float own = keep0 ? acc0[rr] : acc1[rr];
          float val = (own * aF + y[2 + rr] * bF) / lF;
          int q = t * 64 + (qsub << 5) + qp;
          MH[((size_t)(b * SEQ) + q) * DMODEL + h * DHEAD + d] = f2h(val);
        }
      }
      __syncthreads();   // merge slots dead before next seg's Q staging
    }
  }
}

// ---------------- launcher ----------------
extern "C" void kernel_launch(void* const* d_in, const int* in_sizes, int n_in,
                              void* d_out, int out_size, void* d_ws, size_t ws_size,
                              hipStream_t stream) {
  const float* residual = (const float*)d_in[0];
  const float* WQ = (const float*)d_in[1];
  const float* WK = (const float*)d_in[2];
  const float* WV = (const float*)d_in[3];
  const float* WO = (const float*)d_in[4];
  const float* bQ = (const float*)d_in[5];
  const float* bK = (const float*)d_in[6];
  const float* bV = (const float*)d_in[7];
  const float* bO = (const float*)d_in[8];
  float* out = (float*)d_out;

  char* w = (char*)d_ws;
  u16* Xh   = (u16*)(w);                       // 8 MB  [4096][1024]
  u16* Wqkv = (u16*)(w + ((size_t)8 << 20));   // 6 MB  [3072][1024]
  u16* Wo   = (u16*)(w + ((size_t)14 << 20));  // 2 MB  [1024][1024]
  u16* Qd   = (u16*)(w + ((size_t)16 << 20));  // 8 MB  [32][2048][64]
  u16* Kd   = (u16*)(w + ((size_t)24 << 20));  // 8 MB  [32][2048][64]
  u16* Vtd  = (u16*)(w + ((size_t)32 << 20));  // 8 MB  [32][64][2048]
  u16* MH   = (u16*)(w + ((size_t)40 << 20));  // 8 MB  [4096][1024]

  prep_kernel<<<3072, 256, 0, stream>>>(residual, WQ, WK, WV, WO, Xh, Wqkv, Wo);

  gemm_qkv<<<dim3(NQKV / 128, MROWS / 128), 256, 0, stream>>>(
      Xh, Wqkv, bQ, bK, bV, Qd, Kd, Vtd);

  attn_kernel<<<512, 512, 0, stream>>>(Qd, Kd, Vtd, MH);

  gemm_out<<<dim3(DMODEL / 128, MROWS / 128), 256, 0, stream>>>(MH, Wo, bO, out);
}

// Round 14
// 111.080 us; speedup vs baseline: 1.1882x; 1.1882x over previous
//
#include <hip/hip_runtime.h>
#include <stdint.h>

typedef unsigned short u16;
typedef unsigned long long u64;
typedef _Float16 f16;
typedef __attribute__((ext_vector_type(8))) _Float16 f16x8;   // 8 fp16 MFMA frag
typedef __attribute__((ext_vector_type(4))) float f32x4;      // 16x16 MFMA accumulator
typedef __attribute__((ext_vector_type(16))) float f32x16;    // 32x32 MFMA accumulator
typedef __attribute__((ext_vector_type(4))) unsigned short u16x4;
typedef __attribute__((ext_vector_type(8))) unsigned short u16x8;

#define NHEADS 16
#define DMODEL 1024
#define DHEAD 64
#define SEQ 2048
#define NBATCH 2
#define MROWS (NBATCH * SEQ)   /* 4096 */
#define NQKV 3072
#define SCQ 0.18033688011112042f   /* (1/8) * log2(e), folded into Q */

__device__ __forceinline__ u16 f2h(float x) {
  union { f16 h; u16 u; } v;
  v.h = (f16)x;                  // v_cvt_f16_f32, RNE
  return v.u;
}

__device__ __forceinline__ unsigned pk2u(float x, float y) {
  typedef __fp16 fp16x2 __attribute__((ext_vector_type(2)));
  fp16x2 h = __builtin_amdgcn_cvt_pkrtz(x, y);   // v_cvt_pkrtz_f16_f32
  union { fp16x2 h; unsigned u; } v; v.h = h;
  return v.u;
}

__device__ __forceinline__ f16x8 mkfrag(unsigned w0, unsigned w1, unsigned w2, unsigned w3) {
  union { unsigned u[4]; f16x8 f; } t;
  t.u[0] = w0; t.u[1] = w1; t.u[2] = w2; t.u[3] = w3;
  return t.f;
}

// V B-fragment with the custom k-slot map kappa(F,j,hi) = 16F + (j&3) + 8*(j>>2) + 4*hi.
__device__ __forceinline__ f16x8 vfrag(const char* row, int sz, int F, int hib8) {
  union { u64 u[2]; f16x8 f; } t;
  t.u[0] = *(const u64*)(row + (((2 * F) ^ sz) << 4) + hib8);
  t.u[1] = *(const u64*)(row + (((2 * F + 1) ^ sz) << 4) + hib8);
  return t.f;
}

__device__ __forceinline__ void gload_lds16(const void* g, void* l) {
  __builtin_amdgcn_global_load_lds(
      (const __attribute__((address_space(1))) void*)g,
      (__attribute__((address_space(3))) void*)l, 16, 0, 0);
}

// ---------------- merged prep kernel ----------------
// blocks [0,2048): X fp32 -> fp16            (8 elems/thread)
// blocks [2048,2816): W_QKV transpose->fp16  (LDS transpose, coalesced)
// blocks [2816,3072): W_O transpose->fp16
__global__ __launch_bounds__(256) void prep_kernel(
    const float* __restrict__ X,
    const float* __restrict__ WQ, const float* __restrict__ WK,
    const float* __restrict__ WV, const float* __restrict__ WO,
    u16* __restrict__ Xh, u16* __restrict__ Wqkv, u16* __restrict__ Wo) {
  __shared__ u16 lt[64][72];
  int blk = blockIdx.x;
  if (blk < 2048) {
    int i = blk * 256 + threadIdx.x;
    const f32x4* xv = (const f32x4*)(X + (size_t)i * 8);
    f32x4 a = xv[0], b = xv[1];
    u16x8 o;
    o[0] = f2h(a[0]); o[1] = f2h(a[1]); o[2] = f2h(a[2]); o[3] = f2h(a[3]);
    o[4] = f2h(b[0]); o[5] = f2h(b[1]); o[6] = f2h(b[2]); o[7] = f2h(b[3]);
    *(u16x8*)(Xh + (size_t)i * 8) = o;
  } else if (blk < 2816) {
    // W[h][m][d] -> Wqkv[n][m], n = qkv*1024 + h*64 + d
    int bb = blk - 2048;
    int mt = bb & 15, hh = (bb >> 4) & 15, qkv = bb >> 8;
    const float* W = (qkv == 0) ? WQ : (qkv == 1) ? WK : WV;
    int m_in = threadIdx.x >> 2, dq = threadIdx.x & 3;
    const f32x4* sp4 = (const f32x4*)(W + (size_t)hh * (DMODEL * DHEAD) +
                                      (size_t)(mt * 64 + m_in) * DHEAD + dq * 16);
#pragma unroll
    for (int v4 = 0; v4 < 4; ++v4) {
      f32x4 a = sp4[v4];
#pragma unroll
      for (int j = 0; j < 4; ++j) lt[dq * 16 + v4 * 4 + j][m_in] = f2h(a[j]);
    }
    __syncthreads();
    int d_in = threadIdx.x >> 2, mq = threadIdx.x & 3;
    size_t orow = ((size_t)(qkv * 1024 + hh * 64 + d_in)) * DMODEL + mt * 64 + mq * 16;
    u16x8 o0, o1;
#pragma unroll
    for (int j = 0; j < 8; ++j) {
      o0[j] = lt[d_in][mq * 16 + j];
      o1[j] = lt[d_in][mq * 16 + 8 + j];
    }
    *(u16x8*)(Wqkv + orow) = o0;
    *(u16x8*)(Wqkv + orow + 8) = o1;
  } else {
    // WO[e][m] -> Wo[m][e]
    int bb = blk - 2816;
    int mt = bb & 15, et = bb >> 4;
    int e_in = threadIdx.x >> 2, mq = threadIdx.x & 3;
    const f32x4* sp4 = (const f32x4*)(WO + (size_t)(et * 64 + e_in) * DMODEL + mt * 64 + mq * 16);
#pragma unroll
    for (int v4 = 0; v4 < 4; ++v4) {
      f32x4 a = sp4[v4];
#pragma unroll
      for (int j = 0; j < 4; ++j) lt[mq * 16 + v4 * 4 + j][e_in] = f2h(a[j]);
    }
    __syncthreads();
    int m_in = threadIdx.x >> 2, eq = threadIdx.x & 3;
    size_t orow = (size_t)(mt * 64 + m_in) * DMODEL + et * 64 + eq * 16;
    u16x8 o0, o1;
#pragma unroll
    for (int j = 0; j < 8; ++j) {
      o0[j] = lt[m_in][eq * 16 + j];
      o1[j] = lt[m_in][eq * 16 + 8 + j];
    }
    *(u16x8*)(Wo + orow) = o0;
    *(u16x8*)(Wo + orow + 8) = o1;
  }
}

// ---------------- QKV projection GEMM (fp16, N=3072, fused epilogue) ----------------
__global__ __launch_bounds__(256, 2) void gemm_qkv(
    const u16* __restrict__ A, const u16* __restrict__ Bt,
    const float* __restrict__ bq, const float* __restrict__ bk, const float* __restrict__ bv,
    u16* __restrict__ Qo, u16* __restrict__ Ko, u16* __restrict__ Vto) {
  __shared__ u16 lds[2][8192];
  const int tid = threadIdx.x;
  const int wid = tid >> 6, lane = tid & 63, lr = lane & 15, lg = lane >> 4;
  const int wr = wid >> 1, wc = wid & 1;
  const int brow = blockIdx.y * 128, bcol = blockIdx.x * 128;

  f32x4 acc[4][4];
#pragma unroll
  for (int i = 0; i < 4; ++i)
#pragma unroll
    for (int j = 0; j < 4; ++j) acc[i][j] = (f32x4){0.f, 0.f, 0.f, 0.f};

#define STAGE(buf, kt)                                                               \
  {                                                                                  \
    _Pragma("unroll") for (int i = 0; i < 2; ++i) {                                  \
      int idx = tid + i * 256;                                                       \
      gload_lds16(A + (size_t)(brow + (idx >> 2)) * 1024 + (kt) * 32 + (idx & 3) * 8,\
                  (char*)&lds[buf][0] + (wid * 64 + i * 256) * 16);                  \
    }                                                                                \
    _Pragma("unroll") for (int i = 0; i < 2; ++i) {                                  \
      int idx = tid + i * 256;                                                       \
      gload_lds16(Bt + (size_t)(bcol + (idx >> 2)) * 1024 + (kt) * 32 + (idx & 3) * 8,\
                  (char*)&lds[buf][4096] + (wid * 64 + i * 256) * 16);               \
    }                                                                                \
  }

  STAGE(0, 0);
  __syncthreads();
  int cur = 0;
  for (int kt = 0; kt < 32; ++kt) {
    if (kt + 1 < 32) STAGE(cur ^ 1, kt + 1);
    const u16* Ab = &lds[cur][0];
    const u16* Bb = &lds[cur][4096];
    f16x8 a[4], b[4];
#pragma unroll
    for (int ar = 0; ar < 4; ++ar)
      a[ar] = *(const f16x8*)(Ab + (wr * 64 + ar * 16 + lr) * 32 + lg * 8);
#pragma unroll
    for (int bc = 0; bc < 4; ++bc)
      b[bc] = *(const f16x8*)(Bb + (wc * 64 + bc * 16 + lr) * 32 + lg * 8);
#pragma unroll
    for (int ar = 0; ar < 4; ++ar)
#pragma unroll
      for (int bc = 0; bc < 4; ++bc)
        acc[ar][bc] = __builtin_amdgcn_mfma_f32_16x16x32_f16(a[ar], b[bc], acc[ar][bc], 0, 0, 0);
    __syncthreads();
    cur ^= 1;
  }
#undef STAGE

#pragma unroll
  for (int ar = 0; ar < 4; ++ar) {
    int row0 = brow + wr * 64 + ar * 16 + lg * 4;
    int bb = row0 >> 11, s0 = row0 & 2047;
#pragma unroll
    for (int bc = 0; bc < 4; ++bc) {
      int n = bcol + wc * 64 + bc * 16 + lr;
      int qkv = n >> 10, hd = n & 1023, h = hd >> 6, d = hd & 63;
      float bias = ((qkv == 0) ? bq : (qkv == 1) ? bk : bv)[hd];
      if (qkv < 2) {
        u16* dst = qkv ? Ko : Qo;
        float sc = qkv ? 1.f : SCQ;
        size_t base = ((size_t)(bb * NHEADS + h) * SEQ + s0) * DHEAD + d;
#pragma unroll
        for (int r = 0; r < 4; ++r)
          dst[base + (size_t)r * DHEAD] = f2h((acc[ar][bc][r] + bias) * sc);
      } else {
        u16x4 o;
        o[0] = f2h(acc[ar][bc][0] + bias);
        o[1] = f2h(acc[ar][bc][1] + bias);
        o[2] = f2h(acc[ar][bc][2] + bias);
        o[3] = f2h(acc[ar][bc][3] + bias);
        *(u16x4*)(Vto + ((size_t)(bb * NHEADS + h) * DHEAD + d) * SEQ + s0) = o;
      }
    }
  }
}

// ---------------- out-projection GEMM (fp16 in, fp32 out) ----------------
// Retiled 64(M) x 128(N): grid (1024/128=8, 4096/64=64) = 512 blocks -> 2 blocks/CU,
// 8 waves/CU (old 128x128 grid was 256 blocks = 1 block/CU = 4 waves/CU, latency-bound).
// LDS 24KB: A 64x32 @0 (2048 u16), B 128x32 @2048 (4096 u16), double-buffered.
__global__ __launch_bounds__(256, 2) void gemm_out(
    const u16* __restrict__ A, const u16* __restrict__ Bt,
    const float* __restrict__ bo, float* __restrict__ Co) {
  __shared__ u16 lds[2][6144];
  const int tid = threadIdx.x;
  const int wid = tid >> 6, lane = tid & 63, lr = lane & 15, lg = lane >> 4;
  const int wr = wid >> 1, wc = wid & 1;
  const int brow = blockIdx.y * 64, bcol = blockIdx.x * 128;

  f32x4 acc[2][4];
#pragma unroll
  for (int i = 0; i < 2; ++i)
#pragma unroll
    for (int j = 0; j < 4; ++j) acc[i][j] = (f32x4){0.f, 0.f, 0.f, 0.f};

#define OSTAGE(buf, kt)                                                              \
  {                                                                                  \
    {                                                                                \
      int idx = tid;                                                                 \
      gload_lds16(A + (size_t)(brow + (idx >> 2)) * 1024 + (kt) * 32 + (idx & 3) * 8,\
                  (char*)&lds[buf][0] + (wid * 64) * 16);                            \
    }                                                                                \
    _Pragma("unroll") for (int i = 0; i < 2; ++i) {                                  \
      int idx = tid + i * 256;                                                       \
      gload_lds16(Bt + (size_t)(bcol + (idx >> 2)) * 1024 + (kt) * 32 + (idx & 3) * 8,\
                  (char*)&lds[buf][2048] + (wid * 64 + i * 256) * 16);               \
    }                                                                                \
  }

  OSTAGE(0, 0);
  __syncthreads();
  int cur = 0;
  for (int kt = 0; kt < 32; ++kt) {
    if (kt + 1 < 32) OSTAGE(cur ^ 1, kt + 1);
    const u16* Ab = &lds[cur][0];
    const u16* Bb = &lds[cur][2048];
    f16x8 a[2], b[4];
#pragma unroll
    for (int ar = 0; ar < 2; ++ar)
      a[ar] = *(const f16x8*)(Ab + (wr * 32 + ar * 16 + lr) * 32 + lg * 8);
#pragma unroll
    for (int bc = 0; bc < 4; ++bc)
      b[bc] = *(const f16x8*)(Bb + (wc * 64 + bc * 16 + lr) * 32 + lg * 8);
#pragma unroll
    for (int ar = 0; ar < 2; ++ar)
#pragma unroll
      for (int bc = 0; bc < 4; ++bc)
        acc[ar][bc] = __builtin_amdgcn_mfma_f32_16x16x32_f16(a[ar], b[bc], acc[ar][bc], 0, 0, 0);
    __syncthreads();
    cur ^= 1;
  }
#undef OSTAGE

#pragma unroll
  for (int ar = 0; ar < 2; ++ar) {
    int row0 = brow + wr * 32 + ar * 16 + lg * 4;
#pragma unroll
    for (int bc = 0; bc < 4; ++bc) {
      int n = bcol + wc * 64 + bc * 16 + lr;
      float bias = bo[n];
#pragma unroll
      for (int r = 0; r < 4; ++r)
        Co[(size_t)(row0 + r) * DMODEL + n] = acc[ar][bc][r] + bias;
    }
  }
}

// ---------------- flash attention: R12 structure (best measured: 50 us) ----------------
// grid 1024 x 256 thr (4 waves). Block = ONE 64-row q-tile t of one (b,h).
// Wave w: qsub=w&1 (q rows 32*qsub..+31), pairid=w>>1 (even/odd k-tiles, private
// online m/l/acc, merged at end via LDS flash-decoding combine).
// t = perm(q) octet-complement so each CU's 4 round-robin blocks sum to 34 iterations.
// bid = q*32 + bh -> bid&7 = bh&7 pins bh per XCD.
// LDS 32KB: Ke@0 Ko@8K Ve@16K Vo@24K; two-barrier schedule (K hides under PV,
// V under next QK+softmax).
__global__ __launch_bounds__(256, 2) void attn_kernel(
    const u16* __restrict__ Q, const u16* __restrict__ K,
    const u16* __restrict__ Vt, u16* __restrict__ MH) {
  __shared__ char sh8[32768];
  const int tid = threadIdx.x, wid = tid >> 6, lane = tid & 63;
  const int l31 = lane & 31, hi = lane >> 5;
  const int pairid = wid >> 1;          // 0: even k-tiles, 1: odd k-tiles
  const int qsub = wid & 1;             // q 32-row half within the 64-row tile
  const int bid = blockIdx.x;
  const int qidx = bid >> 5, bh = bid & 31;
  const int t = (qidx < 8) ? (31 - qidx) : (qidx < 16) ? (qidx - 8)
              : (qidx < 24) ? (39 - qidx) : (qidx - 16);
  const int h = bh & 15, b = bh >> 4;
  const u16* Qb = Q + (size_t)bh * (SEQ * DHEAD);
  const u16* Kb = K + (size_t)bh * (SEQ * DHEAD);
  const u16* Vb = Vt + (size_t)bh * (DHEAD * SEQ);

  const int sw0 = (l31 ^ (l31 >> 3)) & 7, kz0 = sw0 << 4;
  const int r32 = 32 + l31;
  const int sw1 = (r32 ^ (r32 >> 3)) & 7, kz1 = sw1 << 4;
  const int hib = hi * 16, hib8 = hi * 8;

  // ---- prologue: Q(t)->Ve(16K); K(0)->Ke(0); K(1)->Ko(8K) ----
#pragma unroll
  for (int i = 0; i < 2; ++i) {
    int idx = tid + i * 256, row = idx >> 3;
    int sseg = (idx & 7) ^ ((row ^ (row >> 3)) & 7);
    gload_lds16(Qb + (size_t)(t * 64 + row) * DHEAD + sseg * 8, sh8 + 16384 + idx * 16);
    gload_lds16(Kb + (size_t)row * DHEAD + sseg * 8, sh8 + idx * 16);
    if (t >= 1)
      gload_lds16(Kb + (size_t)(64 + row) * DHEAD + sseg * 8, sh8 + 8192 + idx * 16);
  }
  __syncthreads();

  // Q frags (B-operand): lane -> Q[q = 32*qsub + l31][d = hi*8 + db*16 .. +8]
  f16x8 qf0, qf1, qf2, qf3;
  {
    int row = (qsub << 5) + l31;
    int swz = ((row ^ (row >> 3)) & 7) << 4;
    const char* qb = sh8 + 16384 + row * 128;
    qf0 = *(const f16x8*)(qb + ((hib + 0)  ^ swz));
    qf1 = *(const f16x8*)(qb + ((hib + 32) ^ swz));
    qf2 = *(const f16x8*)(qb + ((hib + 64) ^ swz));
    qf3 = *(const f16x8*)(qb + ((hib + 96) ^ swz));
  }
  __syncthreads();   // Q consumed; Ve free

  // ---- V(0)->Ve(16K); V(1)->Vo(24K) ----
#pragma unroll
  for (int i = 0; i < 2; ++i) {
    int idx = tid + i * 256, row = idx >> 3;
    int sseg = (idx & 7) ^ ((row ^ (row >> 3)) & 7);
    gload_lds16(Vb + (size_t)row * SEQ + sseg * 8, sh8 + 16384 + idx * 16);
    if (t >= 1)
      gload_lds16(Vb + (size_t)row * SEQ + 64 + sseg * 8, sh8 + 24576 + idx * 16);
  }

  f32x16 acc0, acc1;
#pragma unroll
  for (int z = 0; z < 16; ++z) { acc0[z] = 0.f; acc1[z] = 0.f; }
  float m = -1e30f, l = 0.f;
  const int qg = t * 64 + (qsub << 5) + l31;   // this lane's absolute q row
  const int wall = (t >> 1) + 1;

  for (int si = 0; si < wall; ++si) {
    const int kt = 2 * si + pairid;            // this pair's k-tile
    const bool act = (kt <= t);
    f16x8 pa0, pa1, pa2, pa3;

    if (act) {
      const char* kbuf = sh8 + pairid * 8192;

      // ---- QK: S^T[k][q], lane col = q ----
      f32x16 s0, s1;
#pragma unroll
      for (int z = 0; z < 16; ++z) { s0[z] = 0.f; s1[z] = 0.f; }
      {
        const char* kb0 = kbuf + l31 * 128;
        const char* kb1 = kbuf + r32 * 128;
        f16x8 kf;
        __builtin_amdgcn_s_setprio(1);
        kf = *(const f16x8*)(kb0 + ((hib + 0)  ^ kz0)); s0 = __builtin_amdgcn_mfma_f32_32x32x16_f16(kf, qf0, s0, 0, 0, 0);
        kf = *(const f16x8*)(kb0 + ((hib + 32) ^ kz0)); s0 = __builtin_amdgcn_mfma_f32_32x32x16_f16(kf, qf1, s0, 0, 0, 0);
        kf = *(const f16x8*)(kb0 + ((hib + 64) ^ kz0)); s0 = __builtin_amdgcn_mfma_f32_32x32x16_f16(kf, qf2, s0, 0, 0, 0);
        kf = *(const f16x8*)(kb0 + ((hib + 96) ^ kz0)); s0 = __builtin_amdgcn_mfma_f32_32x32x16_f16(kf, qf3, s0, 0, 0, 0);
        kf = *(const f16x8*)(kb1 + ((hib + 0)  ^ kz1)); s1 = __builtin_amdgcn_mfma_f32_32x32x16_f16(kf, qf0, s1, 0, 0, 0);
        kf = *(const f16x8*)(kb1 + ((hib + 32) ^ kz1)); s1 = __builtin_amdgcn_mfma_f32_32x32x16_f16(kf, qf1, s1, 0, 0, 0);
        kf = *(const f16x8*)(kb1 + ((hib + 64) ^ kz1)); s1 = __builtin_amdgcn_mfma_f32_32x32x16_f16(kf, qf2, s1, 0, 0, 0);
        kf = *(const f16x8*)(kb1 + ((hib + 96) ^ kz1)); s1 = __builtin_amdgcn_mfma_f32_32x32x16_f16(kf, qf3, s1, 0, 0, 0);
        __builtin_amdgcn_s_setprio(0);
      }

      // ---- causal mask (diagonal k-tile only): k row = (rr&3)+8*(rr>>2)+4*hi ----
      if (kt == t) {
#pragma unroll
        for (int rr = 0; rr < 16; ++rr) {
          int k0 = kt * 64 + (rr & 3) + 8 * (rr >> 2) + 4 * hi;
          if (k0 > qg) s0[rr] = -1e30f;
          if (k0 + 32 > qg) s1[rr] = -1e30f;
        }
      }

      // ---- per-lane online softmax + 1 shfl_xor(32) per reduction ----
      float tm = s0[0];
#pragma unroll
      for (int rr = 1; rr < 16; ++rr) tm = fmaxf(tm, s0[rr]);
#pragma unroll
      for (int rr = 0; rr < 16; ++rr) tm = fmaxf(tm, s1[rr]);
      tm = fmaxf(tm, __shfl_xor(tm, 32));

      if (!__all(tm <= m + 8.f)) {   // defer-max: rare rescale path
        float m2 = fmaxf(m, tm);
        float al = exp2f(m - m2);
        m = m2;
        l *= al;
#pragma unroll
        for (int rr = 0; rr < 16; ++rr) {
          int qp = (rr & 3) + 8 * (rr >> 2) + 4 * hi;
          float af = __shfl(al, qp);
          acc0[rr] *= af;
          acc1[rr] *= af;
        }
      }

      float rs = 0.f;
#pragma unroll
      for (int rr = 0; rr < 16; ++rr) { s0[rr] = exp2f(s0[rr] - m); rs += s0[rr]; }
#pragma unroll
      for (int rr = 0; rr < 16; ++rr) { s1[rr] = exp2f(s1[rr] - m); rs += s1[rr]; }
      rs += __shfl_xor(rs, 32);
      l += rs;

      // ---- pack P to fp16 A-frags (custom k-slot map, no cross-lane) ----
      pa0 = mkfrag(pk2u(s0[0],  s0[1]),  pk2u(s0[2],  s0[3]),
                   pk2u(s0[4],  s0[5]),  pk2u(s0[6],  s0[7]));
      pa1 = mkfrag(pk2u(s0[8],  s0[9]),  pk2u(s0[10], s0[11]),
                   pk2u(s0[12], s0[13]), pk2u(s0[14], s0[15]));
      pa2 = mkfrag(pk2u(s1[0],  s1[1]),  pk2u(s1[2],  s1[3]),
                   pk2u(s1[4],  s1[5]),  pk2u(s1[6],  s1[7]));
      pa3 = mkfrag(pk2u(s1[8],  s1[9]),  pk2u(s1[10], s1[11]),
                   pk2u(s1[12], s1[13]), pk2u(s1[14], s1[15]));
    }

    __syncthreads();   // barrier A: V(2si),V(2si+1) landed; K regions fully consumed

    // ---- issue next K pair (latency hides under PV + barrier B) ----
    const int e = 2 * si + 2;
    if (e <= t) {
#pragma unroll
      for (int i = 0; i < 2; ++i) {
        int idx = tid + i * 256, row = idx >> 3;
        int sseg = (idx & 7) ^ ((row ^ (row >> 3)) & 7);
        gload_lds16(Kb + (size_t)(e * 64 + row) * DHEAD + sseg * 8, sh8 + idx * 16);
        if (e + 1 <= t)
          gload_lds16(Kb + (size_t)((e + 1) * 64 + row) * DHEAD + sseg * 8,
                      sh8 + 8192 + idx * 16);
      }
    }

    if (act) {
      // ---- PV: O[q][d] += P V, d col = dtile*32 + l31; same k-slot map on V ----
      const char* vbuf = sh8 + 16384 + pairid * 8192;
      const char* vr0 = vbuf + l31 * 128;
      const char* vr1 = vbuf + r32 * 128;
      __builtin_amdgcn_s_setprio(1);
      acc0 = __builtin_amdgcn_mfma_f32_32x32x16_f16(pa0, vfrag(vr0, sw0, 0, hib8), acc0, 0, 0, 0);
      acc0 = __builtin_amdgcn_mfma_f32_32x32x16_f16(pa1, vfrag(vr0, sw0, 1, hib8), acc0, 0, 0, 0);
      acc0 = __builtin_amdgcn_mfma_f32_32x32x16_f16(pa2, vfrag(vr0, sw0, 2, hib8), acc0, 0, 0, 0);
      acc0 = __builtin_amdgcn_mfma_f32_32x32x16_f16(pa3, vfrag(vr0, sw0, 3, hib8), acc0, 0, 0, 0);
      acc1 = __builtin_amdgcn_mfma_f32_32x32x16_f16(pa0, vfrag(vr1, sw1, 0, hib8), acc1, 0, 0, 0);
      acc1 = __builtin_amdgcn_mfma_f32_32x32x16_f16(pa1, vfrag(vr1, sw1, 1, hib8), acc1, 0, 0, 0);
      acc1 = __builtin_amdgcn_mfma_f32_32x32x16_f16(pa2, vfrag(vr1, sw1, 2, hib8), acc1, 0, 0, 0);
      acc1 = __builtin_amdgcn_mfma_f32_32x32x16_f16(pa3, vfrag(vr1, sw1, 3, hib8), acc1, 0, 0, 0);
      __builtin_amdgcn_s_setprio(0);
    }

    __syncthreads();   // barrier B: V consumed by all; K staging drained

    // ---- issue next V pair (latency hides under next QK + softmax) ----
    if (e <= t) {
#pragma unroll
      for (int i = 0; i < 2; ++i) {
        int idx = tid + i * 256, row = idx >> 3;
        int sseg = (idx & 7) ^ ((row ^ (row >> 3)) & 7);
        gload_lds16(Vb + (size_t)row * SEQ + e * 64 + sseg * 8, sh8 + 16384 + idx * 16);
        if (e + 1 <= t)
          gload_lds16(Vb + (size_t)row * SEQ + (e + 1) * 64 + sseg * 8,
                      sh8 + 24576 + idx * 16);
      }
    }
  }

  // ---- merge the two pairs' partial (m,l,acc) + store (flash-decoding combine) ----
  {
    // pair0 keeps d=l31 (acc0), exports acc1; pair1 keeps d=32+l31 (acc1), exports acc0.
    // Export regions overlay dead K/V buffers: pair0 -> [0,9216), pair1 -> [16384,+9216).
    const int slot = (qsub << 6) | (hi << 5) | l31;   // 0..127
    float* z = (float*)(sh8 + (pairid ? 16384 : 0)) + slot * 18;
    z[0] = m; z[1] = l;
#pragma unroll
    for (int rr = 0; rr < 16; ++rr) z[2 + rr] = pairid ? acc0[rr] : acc1[rr];
    __syncthreads();
    const float* y = (const float*)(sh8 + (pairid ? 0 : 16384)) + slot * 18;
    float mb = y[0], lb = y[1];
    float mM = fmaxf(m, mb);
    float aw = exp2f(m - mM), bw = exp2f(mb - mM);
    float lM = l * aw + lb * bw;
    const int d = pairid ? (32 + l31) : l31;
#pragma unroll
    for (int rr = 0; rr < 16; ++rr) {
      int qp = (rr & 3) + 8 * (rr >> 2) + 4 * hi;
      float aF = __shfl(aw, qp), bF = __shfl(bw, qp), lF = __shfl(lM, qp);
      float own = pairid ? acc1[rr] : acc0[rr];
      float val = (own * aF + y[2 + rr] * bF) / lF;
      int q = t * 64 + (qsub << 5) + qp;
      MH[((size_t)(b * SEQ) + q) * DMODEL + h * DHEAD + d] = f2h(val);
    }
  }
}

// ---------------- launcher ----------------
extern "C" void kernel_launch(void* const* d_in, const int* in_sizes, int n_in,
                              void* d_out, int out_size, void* d_ws, size_t ws_size,
                              hipStream_t stream) {
  const float* residual = (const float*)d_in[0];
  const float* WQ = (const float*)d_in[1];
  const float* WK = (const float*)d_in[2];
  const float* WV = (const float*)d_in[3];
  const float* WO = (const float*)d_in[4];
  const float* bQ = (const float*)d_in[5];
  const float* bK = (const float*)d_in[6];
  const float* bV = (const float*)d_in[7];
  const float* bO = (const float*)d_in[8];
  float* out = (float*)d_out;

  char* w = (char*)d_ws;
  u16* Xh   = (u16*)(w);                       // 8 MB  [4096][1024]
  u16* Wqkv = (u16*)(w + ((size_t)8 << 20));   // 6 MB  [3072][1024]
  u16* Wo   = (u16*)(w + ((size_t)14 << 20));  // 2 MB  [1024][1024]
  u16* Qd   = (u16*)(w + ((size_t)16 << 20));  // 8 MB  [32][2048][64]
  u16* Kd   = (u16*)(w + ((size_t)24 << 20));  // 8 MB  [32][2048][64]
  u16* Vtd  = (u16*)(w + ((size_t)32 << 20));  // 8 MB  [32][64][2048]
  u16* MH   = (u16*)(w + ((size_t)40 << 20));  // 8 MB  [4096][1024]

  prep_kernel<<<3072, 256, 0, stream>>>(residual, WQ, WK, WV, WO, Xh, Wqkv, Wo);

  gemm_qkv<<<dim3(NQKV / 128, MROWS / 128), 256, 0, stream>>>(
      Xh, Wqkv, bQ, bK, bV, Qd, Kd, Vtd);

  attn_kernel<<<1024, 256, 0, stream>>>(Qd, Kd, Vtd, MH);

  gemm_out<<<dim3(DMODEL / 128, MROWS / 64), 256, 0, stream>>>(MH, Wo, bO, out);
}